// Round 2
// baseline (199.219 us; speedup 1.0000x reference)
//
#include <hip/hip_runtime.h>
#include <hip/hip_bf16.h>

using short8   = __attribute__((ext_vector_type(8))) short;
using ushort4v = __attribute__((ext_vector_type(4))) unsigned short;
using f32x4    = __attribute__((ext_vector_type(4))) float;

static constexpr int CDIM = 512;
static constexpr int SEQ  = 1024;
static constexpr int NQKV = 1536;

__device__ __forceinline__ short f2bf(float f) {
  unsigned u = __builtin_bit_cast(unsigned, f);
  u = (u + 0x7fffu + ((u >> 16) & 1u)) >> 16;   // RNE; values finite here
  return (short)(unsigned short)u;
}

#define GLOAD_LDS16(gp, lp)                                                              \
  __builtin_amdgcn_global_load_lds((const __attribute__((address_space(1))) void*)(gp),  \
                                   (__attribute__((address_space(3))) void*)(lp), 16, 0, 0)

// ---- fused cast+transpose: src f32 [b][R][C] -> dst bf16 [b][C][R] ----
__global__ __launch_bounds__(256) void transpose_cast(const float* __restrict__ src,
                                                      short* __restrict__ dst,
                                                      int R, int C) {
  __shared__ float tile[64 * 65];          // transposed tile [c][r], pitch 65: conflict-free
  const int b  = blockIdx.z;
  const int r0 = blockIdx.y * 64;
  const int c0 = blockIdx.x * 64;
  const float* s = src + (size_t)b * R * C;
  short*       d = dst + (size_t)b * R * C;
  const int t  = threadIdx.x;
  const int rr = t >> 4;                    // 0..15
  const int c4 = (t & 15) * 4;
#pragma unroll
  for (int i = 0; i < 4; ++i) {
    const int r = rr + i * 16;
    f32x4 v = *(const f32x4*)(s + (size_t)(r0 + r) * C + c0 + c4);
#pragma unroll
    for (int j = 0; j < 4; ++j) tile[(c4 + j) * 65 + r] = v[j];   // scalar, 2-way max
  }
  __syncthreads();
  const int r8 = (t & 7) * 8;
#pragma unroll
  for (int i = 0; i < 2; ++i) {
    const int c = (t >> 3) + i * 32;
    short8 pk;
#pragma unroll
    for (int j = 0; j < 8; ++j) pk[j] = f2bf(tile[c * 65 + r8 + j]);
    *(short8*)(d + (size_t)(c0 + c) * R + r0 + r8) = pk;          // 16B coalesced store
  }
}

// ---- QKV projection: [8192,512] x [512,1536] -> [8192,1536] bf16 (+f32 bias)
__global__ __launch_bounds__(256) void qkv_gemm(const short* __restrict__ Xq,
                                                const short* __restrict__ Xkv,
                                                const short* __restrict__ Wt,
                                                const float* __restrict__ bias,
                                                short* __restrict__ QKV) {
  __shared__ short Asm[128 * 32];
  __shared__ short Bsm[128 * 32];
  const int n0 = blockIdx.x * 128;
  const int m0 = blockIdx.y * 128;
  const short* A = (n0 < CDIM) ? Xq : Xkv;
  const int t = threadIdx.x;
  const int w = t >> 6, l = t & 63;
  const int wm = w & 1, wn = w >> 1;
  const int lc = l & 15, lr = l >> 4;

  f32x4 acc[4][4];
#pragma unroll
  for (int i = 0; i < 4; ++i)
#pragma unroll
    for (int j = 0; j < 4; ++j) acc[i][j] = (f32x4){0.f, 0.f, 0.f, 0.f};

  for (int kb = 0; kb < 16; ++kb) {
    const int k0 = kb * 32;
#pragma unroll
    for (int i = 0; i < 2; ++i) {
      const int Qi = (w * 2 + i) * 64 + l;     // LDS slot Qi -> row Qi>>2, k-quad Qi&3
      const int m = Qi >> 2, kq = Qi & 3;
      GLOAD_LDS16(A  + (size_t)(m0 + m) * CDIM + k0 + kq * 8, &Asm[(w * 2 + i) * 512]);
      GLOAD_LDS16(Wt + (size_t)(n0 + m) * CDIM + k0 + kq * 8, &Bsm[(w * 2 + i) * 512]);
    }
    __syncthreads();
    short8 af[4], bfr[4];
#pragma unroll
    for (int mt = 0; mt < 4; ++mt)
      af[mt] = *(const short8*)(&Asm[(wm * 64 + mt * 16 + lc) * 32 + lr * 8]);
#pragma unroll
    for (int nt = 0; nt < 4; ++nt)
      bfr[nt] = *(const short8*)(&Bsm[(wn * 64 + nt * 16 + lc) * 32 + lr * 8]);
#pragma unroll
    for (int mt = 0; mt < 4; ++mt)
#pragma unroll
      for (int nt = 0; nt < 4; ++nt)
        acc[mt][nt] = __builtin_amdgcn_mfma_f32_16x16x32_bf16(af[mt], bfr[nt], acc[mt][nt], 0, 0, 0);
    __syncthreads();
  }
#pragma unroll
  for (int nt = 0; nt < 4; ++nt) {
    const int n = n0 + wn * 64 + nt * 16 + lc;
    const float bv = bias[n];
#pragma unroll
    for (int mt = 0; mt < 4; ++mt) {
      const int m = m0 + wm * 64 + mt * 16 + lr * 4;
#pragma unroll
      for (int r = 0; r < 4; ++r)
        QKV[(size_t)(m + r) * NQKV + n] = f2bf(acc[mt][nt][r] + bv);
    }
  }
}

// ---- flash attention: one block = 64 q-rows of one (b,h); K-tile = 64 ----
__global__ __launch_bounds__(256) void flash_attn(const short* __restrict__ QKV,
                                                  float* __restrict__ out) {
  __shared__ alignas(16) short smem[12288];  // 24 KiB
  short* Ksm = smem;                         // K tile  [s][d] swizzled, 8 KiB
  short* Vsm = smem + 4096;                  // V^T     [d][s] swizzled, 8 KiB
  short* Psm = smem + 8192;                  // P per-wave [q][kk] swizzled, 8 KiB
  const int b = blockIdx.z, h = blockIdx.y;
  const int q0 = blockIdx.x * 64;
  const int t = threadIdx.x;
  const int w = t >> 6, l = t & 63;
  const int lc = l & 15, lr = l >> 4;
  const short* base = QKV + (size_t)b * SEQ * NQKV + h * 64;

  short8 aq[2];                              // Q A-frags (16 q-rows x 64 d), in regs
  {
    const short* qrow = base + (size_t)(q0 + w * 16 + lc) * NQKV;
    aq[0] = *(const short8*)(qrow + lr * 8);
    aq[1] = *(const short8*)(qrow + 32 + lr * 8);
  }

  float m_i[4], l_i[4];
  f32x4 Oac[4];
#pragma unroll
  for (int r = 0; r < 4; ++r) { m_i[r] = -INFINITY; l_i[r] = 0.f; }
#pragma unroll
  for (int dt = 0; dt < 4; ++dt) Oac[dt] = (f32x4){0.f, 0.f, 0.f, 0.f};

  const float kscale = 0.125f * 1.44269504088896341f;   // scale * log2(e)

  for (int it = 0; it < 16; ++it) {
    const int kk0 = it * 64;
    // K tile direct-to-LDS; swizzle encoded on the global side (lane-arbitrary)
#pragma unroll
    for (int i = 0; i < 2; ++i) {
      const int Qi = (w * 2 + i) * 64 + l;
      const int s = Qi >> 3, dq = (Qi & 7) ^ (s & 7);
      GLOAD_LDS16(base + CDIM + (size_t)(kk0 + s) * NQKV + dq * 8, &Ksm[(w * 2 + i) * 512]);
    }
    // V^T via VGPR transpose, XOR-swizzled
#pragma unroll
    for (int i = 0; i < 2; ++i) {
      const int Qi = i * 256 + t;
      const int s = Qi >> 3, dq = Qi & 7;
      short8 v = *(const short8*)(base + 2 * CDIM + (size_t)(kk0 + s) * NQKV + dq * 8);
#pragma unroll
      for (int jd = 0; jd < 8; ++jd) {
        const int d = dq * 8 + jd;
        Vsm[(d * 8 + ((s >> 3) ^ (d & 7))) * 8 + (s & 7)] = (short)v[jd];
      }
    }
    __syncthreads();

    // S = Q K^T  (per wave: 16 q x 64 kk)
    f32x4 sc[4];
#pragma unroll
    for (int nt = 0; nt < 4; ++nt) {
      sc[nt] = (f32x4){0.f, 0.f, 0.f, 0.f};
#pragma unroll
      for (int c = 0; c < 2; ++c) {
        const int srow = nt * 16 + lc;
        const int dq = c * 4 + lr;
        short8 bk = *(const short8*)(&Ksm[(srow * 8 + (dq ^ (srow & 7))) * 8]);
        sc[nt] = __builtin_amdgcn_mfma_f32_16x16x32_bf16(aq[c], bk, sc[nt], 0, 0, 0);
      }
    }

    // online softmax; row q = lr*4+r lives on the 16 lanes sharing lr
    float rmax[4], mnew[4], alpha[4], rs[4];
#pragma unroll
    for (int r = 0; r < 4; ++r)
      rmax[r] = fmaxf(fmaxf(sc[0][r], sc[1][r]), fmaxf(sc[2][r], sc[3][r]));
#pragma unroll
    for (int off = 1; off < 16; off <<= 1)
#pragma unroll
      for (int r = 0; r < 4; ++r)
        rmax[r] = fmaxf(rmax[r], __shfl_xor(rmax[r], off, 64));
#pragma unroll
    for (int r = 0; r < 4; ++r) {
      mnew[r]  = fmaxf(m_i[r], rmax[r]);
      alpha[r] = __builtin_amdgcn_exp2f((m_i[r] - mnew[r]) * kscale);
      rs[r] = 0.f;
    }
#pragma unroll
    for (int nt = 0; nt < 4; ++nt) {
      const int kk = nt * 16 + lc;
      const int kq = kk >> 3;
#pragma unroll
      for (int r = 0; r < 4; ++r) {
        float p = __builtin_amdgcn_exp2f((sc[nt][r] - mnew[r]) * kscale);
        rs[r] += p;
        const int qq = lr * 4 + r;
        Psm[w * 1024 + (qq * 8 + (kq ^ (qq & 7))) * 8 + (kk & 7)] = f2bf(p);
      }
    }
#pragma unroll
    for (int off = 1; off < 16; off <<= 1)
#pragma unroll
      for (int r = 0; r < 4; ++r)
        rs[r] += __shfl_xor(rs[r], off, 64);
#pragma unroll
    for (int r = 0; r < 4; ++r) {
      l_i[r] = l_i[r] * alpha[r] + rs[r];
      m_i[r] = mnew[r];
    }
#pragma unroll
    for (int dt = 0; dt < 4; ++dt)
#pragma unroll
      for (int r = 0; r < 4; ++r) Oac[dt][r] *= alpha[r];

    // O += P V   (A = P from LDS in A-layout, B = V^T)
    short8 ap[2];
#pragma unroll
    for (int c = 0; c < 2; ++c) {
      const int kq = c * 4 + lr;
      ap[c] = *(const short8*)(&Psm[w * 1024 + (lc * 8 + (kq ^ (lc & 7))) * 8]);
    }
#pragma unroll
    for (int dt = 0; dt < 4; ++dt) {
#pragma unroll
      for (int c = 0; c < 2; ++c) {
        const int d = dt * 16 + lc;
        const int sq = c * 4 + lr;
        short8 bv = *(const short8*)(&Vsm[(d * 8 + (sq ^ (d & 7))) * 8]);
        Oac[dt] = __builtin_amdgcn_mfma_f32_16x16x32_bf16(ap[c], bv, Oac[dt], 0, 0, 0);
      }
    }
    __syncthreads();
  }

  // epilogue: O^T bounce through LDS as f32 -> coalesced float4 stores
  float rinv[4];
#pragma unroll
  for (int r = 0; r < 4; ++r) rinv[r] = 1.f / l_i[r];
  float* fsm = (float*)smem;                 // [64 d][68 pitch] f32 = 17.4 KiB
#pragma unroll
  for (int dt = 0; dt < 4; ++dt) {
    const int d = dt * 16 + lc;
    f32x4 pk;
#pragma unroll
    for (int r = 0; r < 4; ++r) pk[r] = Oac[dt][r] * rinv[r];
    *(f32x4*)(&fsm[d * 68 + w * 16 + lr * 4]) = pk;
  }
  __syncthreads();
  float* outp = out + (size_t)b * CDIM * SEQ + (size_t)(h * 64) * SEQ + q0;
#pragma unroll
  for (int i = 0; i < 4; ++i) {
    const int idx = i * 256 + t;
    const int d = idx >> 4, qg = idx & 15;
    f32x4 vv = *(const f32x4*)(&fsm[d * 68 + qg * 4]);
    *(f32x4*)(outp + (size_t)d * SEQ + qg * 4) = vv;
  }
}

extern "C" void kernel_launch(void* const* d_in, const int* in_sizes, int n_in,
                              void* d_out, int out_size, void* d_ws, size_t ws_size,
                              hipStream_t stream) {
  const float* query = (const float*)d_in[0];   // f32 [8,512,1024]
  const float* keyv  = (const float*)d_in[1];   // f32 [8,512,1024]
  const float* Wqkv  = (const float*)d_in[2];   // f32 [512,1536]
  const float* bqkv  = (const float*)d_in[3];   // f32 [1536]
  float* out = (float*)d_out;                   // f32 [8,512,1024]
  short* ws  = (short*)d_ws;

  short* Xq_t  = ws;              // bf16 [8192,512]
  short* Xkv_t = ws + 4194304;    // bf16 [8192,512]
  short* W_t   = ws + 8388608;    // bf16 [1536,512]
  short* QKV   = ws + 9175040;    // bf16 [8192,1536]

  transpose_cast<<<dim3(16, 8, 8), 256, 0, stream>>>(query, Xq_t, 512, 1024);
  transpose_cast<<<dim3(16, 8, 8), 256, 0, stream>>>(keyv,  Xkv_t, 512, 1024);
  transpose_cast<<<dim3(24, 8, 1), 256, 0, stream>>>(Wqkv,  W_t,   512, 1536);
  qkv_gemm<<<dim3(12, 64, 1), 256, 0, stream>>>(Xq_t, Xkv_t, W_t, bqkv, QKV);
  flash_attn<<<dim3(16, 8, 8), 256, 0, stream>>>(QKV, out);
}

// Round 3
// 160.426 us; speedup vs baseline: 1.2418x; 1.2418x over previous
//
#include <hip/hip_runtime.h>
#include <hip/hip_bf16.h>

using short4v = __attribute__((ext_vector_type(4))) short;
using short8  = __attribute__((ext_vector_type(8))) short;
using uint2v  = __attribute__((ext_vector_type(2))) unsigned int;
using f32x4   = __attribute__((ext_vector_type(4))) float;

static constexpr int CDIM = 512;
static constexpr int SEQ  = 1024;

__device__ __forceinline__ short f2bf(float f) {
  unsigned u = __builtin_bit_cast(unsigned, f);
  u = (u + 0x7fffu + ((u >> 16) & 1u)) >> 16;   // RNE; values finite here
  return (short)(unsigned short)u;
}
__device__ __forceinline__ unsigned pack_bf16(float a, float b) {
  return (unsigned)(unsigned short)f2bf(a) | ((unsigned)(unsigned short)f2bf(b) << 16);
}

#define GLOAD_LDS16(gp, lp)                                                              \
  __builtin_amdgcn_global_load_lds((const __attribute__((address_space(1))) void*)(gp),  \
                                   (__attribute__((address_space(3))) void*)(lp), 16, 0, 0)
#define MFMA16(a, b, c) __builtin_amdgcn_mfma_f32_16x16x32_bf16((a), (b), (c), 0, 0, 0)

// ---- fused cast+transpose: src f32 [b][R][C] -> dst bf16 [b][C][R] ----
__global__ __launch_bounds__(256) void transpose_cast(const float* __restrict__ src,
                                                      short* __restrict__ dst,
                                                      int R, int C) {
  __shared__ float tile[64 * 65];
  const int b  = blockIdx.z;
  const int r0 = blockIdx.y * 64;
  const int c0 = blockIdx.x * 64;
  const float* s = src + (size_t)b * R * C;
  short*       d = dst + (size_t)b * R * C;
  const int t  = threadIdx.x;
  const int rr = t >> 4;
  const int c4 = (t & 15) * 4;
#pragma unroll
  for (int i = 0; i < 4; ++i) {
    const int r = rr + i * 16;
    f32x4 v = *(const f32x4*)(s + (size_t)(r0 + r) * C + c0 + c4);
#pragma unroll
    for (int j = 0; j < 4; ++j) tile[(c4 + j) * 65 + r] = v[j];
  }
  __syncthreads();
  const int r8 = (t & 7) * 8;
#pragma unroll
  for (int i = 0; i < 2; ++i) {
    const int c = (t >> 3) + i * 32;
    short8 pk;
#pragma unroll
    for (int j = 0; j < 8; ++j) pk[j] = f2bf(tile[c * 65 + r8 + j]);
    *(short8*)(d + (size_t)(c0 + c) * R + r0 + r8) = pk;
  }
}

// ---- QKV projection -> head-major layouts:
//   Qg,Kg: [b*8+h][s(1024)][d(64)]   Vt: [b*8+h][d(64)][s(1024)]
__global__ __launch_bounds__(256) void qkv_gemm(const short* __restrict__ Xq,
                                                const short* __restrict__ Xkv,
                                                const short* __restrict__ Wt,
                                                const float* __restrict__ bias,
                                                short* __restrict__ Qg,
                                                short* __restrict__ Kg,
                                                short* __restrict__ Vt) {
  __shared__ short Asm[128 * 32];
  __shared__ short Bsm[128 * 32];
  __shared__ short epi[4608];                 // 4 waves x 16 x 72
  const int n0 = blockIdx.x * 128;
  const int m0 = blockIdx.y * 128;
  const short* A = (n0 < CDIM) ? Xq : Xkv;
  const int t = threadIdx.x;
  const int w = t >> 6, l = t & 63;
  const int wm = w & 1, wn = w >> 1;
  const int lc = l & 15, lr = l >> 4;

  f32x4 acc[4][4];
#pragma unroll
  for (int i = 0; i < 4; ++i)
#pragma unroll
    for (int j = 0; j < 4; ++j) acc[i][j] = (f32x4){0.f, 0.f, 0.f, 0.f};

  for (int kb = 0; kb < 16; ++kb) {
    const int k0 = kb * 32;
#pragma unroll
    for (int i = 0; i < 2; ++i) {
      const int Qi = (w * 2 + i) * 64 + l;
      const int m = Qi >> 2, kq = Qi & 3;
      GLOAD_LDS16(A  + (size_t)(m0 + m) * CDIM + k0 + kq * 8, &Asm[(w * 2 + i) * 512]);
      GLOAD_LDS16(Wt + (size_t)(n0 + m) * CDIM + k0 + kq * 8, &Bsm[(w * 2 + i) * 512]);
    }
    __syncthreads();
    short8 af[4], bfr[4];
#pragma unroll
    for (int mt = 0; mt < 4; ++mt)
      af[mt] = *(const short8*)(&Asm[(wm * 64 + mt * 16 + lc) * 32 + lr * 8]);
#pragma unroll
    for (int nt = 0; nt < 4; ++nt)
      bfr[nt] = *(const short8*)(&Bsm[(wn * 64 + nt * 16 + lc) * 32 + lr * 8]);
#pragma unroll
    for (int mt = 0; mt < 4; ++mt)
#pragma unroll
      for (int nt = 0; nt < 4; ++nt)
        acc[mt][nt] = MFMA16(af[mt], bfr[nt], acc[mt][nt]);
    __syncthreads();
  }

  // ---- epilogue: head-major, vectorized ----
  const int N0 = n0 + wn * 64, M0 = m0 + wm * 64;
  const int hg = N0 >> 6;                 // 0..23
  const int part = hg >> 3, hh = hg & 7;
  const int bb = M0 >> 10, s0 = M0 & 1023;
  float bv[4];
#pragma unroll
  for (int nt = 0; nt < 4; ++nt) bv[nt] = bias[N0 + nt * 16 + lc];

  if (part < 2) {
    short* slab = epi + w * 1152;         // [16 m][72]
    short* obase = (part ? Kg : Qg) + (size_t)(bb * 8 + hh) * 65536 + (size_t)s0 * 64;
#pragma unroll
    for (int mt = 0; mt < 4; ++mt) {
#pragma unroll
      for (int nt = 0; nt < 4; ++nt)
#pragma unroll
        for (int r = 0; r < 4; ++r)
          slab[(lr * 4 + r) * 72 + nt * 16 + lc] = f2bf(acc[mt][nt][r] + bv[nt]);
      __builtin_amdgcn_s_waitcnt(0);      // drain lgkm before re-reading slab
#pragma unroll
      for (int i = 0; i < 2; ++i) {
        const int slot = i * 64 + l;
        const int m_l = slot >> 3, n8 = (slot & 7) * 8;
        short8 vv = *(const short8*)(&slab[m_l * 72 + n8]);
        *(short8*)(obase + (size_t)(mt * 16 + m_l) * 64 + n8) = vv;
      }
    }
  } else {
    short* obase = Vt + (size_t)(bb * 8 + hh) * 65536 + s0;
#pragma unroll
    for (int mt = 0; mt < 4; ++mt)
#pragma unroll
      for (int nt = 0; nt < 4; ++nt) {
        short4v pk;
#pragma unroll
        for (int r = 0; r < 4; ++r) pk[r] = f2bf(acc[mt][nt][r] + bv[nt]);
        *(short4v*)(obase + (size_t)(nt * 16 + lc) * 1024 + mt * 16 + lr * 4) = pk;
      }
  }
}

// ---- flash attention (S^T orientation): block = 64 q of one (b,h) ----
__global__ __launch_bounds__(256) void flash_attn(const short* __restrict__ Qg,
                                                  const short* __restrict__ Kg,
                                                  const short* __restrict__ Vt,
                                                  float* __restrict__ out) {
  __shared__ alignas(16) short smem[12800];   // 25.6 KB
  short* Ksm = smem;                          // [64 s][8 chunk swz][8] 8KB
  short* Vsm = smem + 4096;                   // [64 d][8 chunk swz][8] 8KB
  const int b = blockIdx.z, h = blockIdx.y;
  const int q0 = blockIdx.x * 64;
  const int bh = b * 8 + h;
  const int t = threadIdx.x;
  const int w = t >> 6, l = t & 63;
  const int quad = l >> 4, l15 = l & 15;
  short* Psm = smem + 8192 + w * 1152;        // per-wave [16 q][72]

  const short* Qbase = Qg + (size_t)bh * 65536;
  const short* Kbase = Kg + (size_t)bh * 65536;
  const short* Vbase = Vt + (size_t)bh * 65536;

  short8 bq[2];                               // Q B-frags: n=q (l15), k=d
  {
    const short* qrow = Qbase + (size_t)(q0 + w * 16 + l15) * 64;
    bq[0] = *(const short8*)(qrow + quad * 8);
    bq[1] = *(const short8*)(qrow + 32 + quad * 8);
  }

  float m_i = -INFINITY, l_i = 0.f;
  f32x4 Oac[4];
#pragma unroll
  for (int dt = 0; dt < 4; ++dt) Oac[dt] = (f32x4){0.f, 0.f, 0.f, 0.f};
  const float kscale = 0.125f * 1.44269504088896341f;   // scale * log2(e)

  for (int it = 0; it < 16; ++it) {
    const int kk0 = it * 64;
#pragma unroll
    for (int i = 0; i < 2; ++i) {
      const int Qi = (w * 2 + i) * 64 + l;
      const int sr = Qi >> 3, u = Qi & 7;     // slot (row, chunk); global chunk = u^(row&7)
      GLOAD_LDS16(Kbase + (size_t)(kk0 + sr) * 64 + (u ^ (sr & 7)) * 8, &Ksm[Qi * 8]);
      GLOAD_LDS16(Vbase + (size_t)sr * 1024 + kk0 + (u ^ (sr & 7)) * 8, &Vsm[Qi * 8]);
    }
    __syncthreads();

    // S^T = K Q^T : per wave 64 kk x 16 q
    f32x4 st[4];
#pragma unroll
    for (int nt = 0; nt < 4; ++nt) {
      st[nt] = (f32x4){0.f, 0.f, 0.f, 0.f};
#pragma unroll
      for (int c = 0; c < 2; ++c) {
        const int srow = nt * 16 + l15;
        short8 kf = *(const short8*)(&Ksm[(srow * 8 + ((c * 4 + quad) ^ (srow & 7))) * 8]);
        st[nt] = MFMA16(kf, bq[c], st[nt]);
      }
    }

    // online softmax over kk (rows); q = q0+16w+l15 fixed per lane
    float rmax = st[0][0];
#pragma unroll
    for (int nt = 0; nt < 4; ++nt)
#pragma unroll
      for (int r = 0; r < 4; ++r) rmax = fmaxf(rmax, st[nt][r]);
    rmax = fmaxf(rmax, __shfl_xor(rmax, 16, 64));
    rmax = fmaxf(rmax, __shfl_xor(rmax, 32, 64));
    const float mnew = fmaxf(m_i, rmax);
    const float alpha = __builtin_amdgcn_exp2f((m_i - mnew) * kscale);
    float p[4][4];
    float rs = 0.f;
#pragma unroll
    for (int nt = 0; nt < 4; ++nt)
#pragma unroll
      for (int r = 0; r < 4; ++r) {
        p[nt][r] = __builtin_amdgcn_exp2f((st[nt][r] - mnew) * kscale);
        rs += p[nt][r];
      }
    rs += __shfl_xor(rs, 16, 64);
    rs += __shfl_xor(rs, 32, 64);
    l_i = l_i * alpha + rs;
    m_i = mnew;
#pragma unroll
    for (int dt = 0; dt < 4; ++dt)
#pragma unroll
      for (int r = 0; r < 4; ++r) Oac[dt][r] *= alpha;

    // P^T (C-layout) -> row-major P[q][kk] in per-wave LDS: b64 writes, pitch 72
#pragma unroll
    for (int nt = 0; nt < 4; ++nt) {
      uint2v pk;
      pk[0] = pack_bf16(p[nt][0], p[nt][1]);
      pk[1] = pack_bf16(p[nt][2], p[nt][3]);
      *(uint2v*)(&Psm[l15 * 72 + (nt * 4 + quad) * 4]) = pk;
    }

    // O^T += V^T P : A = V^T frags (b128), B = P frags (b128)
#pragma unroll
    for (int c = 0; c < 2; ++c) {
      short8 pb = *(const short8*)(&Psm[l15 * 72 + (c * 8 + quad * 2) * 4]);
#pragma unroll
      for (int dt = 0; dt < 4; ++dt) {
        const int drow = dt * 16 + l15;
        short8 vf = *(const short8*)(&Vsm[(drow * 8 + ((c * 4 + quad) ^ (drow & 7))) * 8]);
        Oac[dt] = MFMA16(vf, pb, Oac[dt]);
      }
    }
    __syncthreads();
  }

  // epilogue: O^T[d][q] -> out[b][h*64+d][q], 64B-segment dword stores
  const float rinv = 1.f / l_i;
  float* ob = out + ((size_t)(b * 512 + h * 64)) * 1024 + q0 + w * 16 + l15;
#pragma unroll
  for (int dt = 0; dt < 4; ++dt)
#pragma unroll
    for (int r = 0; r < 4; ++r)
      ob[(size_t)(dt * 16 + quad * 4 + r) * 1024] = Oac[dt][r] * rinv;
}

extern "C" void kernel_launch(void* const* d_in, const int* in_sizes, int n_in,
                              void* d_out, int out_size, void* d_ws, size_t ws_size,
                              hipStream_t stream) {
  const float* query = (const float*)d_in[0];   // f32 [8,512,1024]
  const float* keyv  = (const float*)d_in[1];   // f32 [8,512,1024]
  const float* Wqkv  = (const float*)d_in[2];   // f32 [512,1536]
  const float* bqkv  = (const float*)d_in[3];   // f32 [1536]
  float* out = (float*)d_out;                   // f32 [8,512,1024]
  short* ws  = (short*)d_ws;

  short* Xq_t  = ws;               // bf16 [8192,512]
  short* Xkv_t = ws + 4194304;     // bf16 [8192,512]
  short* W_t   = ws + 8388608;     // bf16 [1536,512]
  short* Qg    = ws + 9175040;     // bf16 [64][1024][64]
  short* Kg    = ws + 13369344;    // bf16 [64][1024][64]
  short* Vt    = ws + 17563648;    // bf16 [64][64][1024]

  transpose_cast<<<dim3(16, 8, 8), 256, 0, stream>>>(query, Xq_t, 512, 1024);
  transpose_cast<<<dim3(16, 8, 8), 256, 0, stream>>>(keyv,  Xkv_t, 512, 1024);
  transpose_cast<<<dim3(24, 8, 1), 256, 0, stream>>>(Wqkv,  W_t,   512, 1536);
  qkv_gemm<<<dim3(12, 64, 1), 256, 0, stream>>>(Xq_t, Xkv_t, W_t, bqkv, Qg, Kg, Vt);
  flash_attn<<<dim3(16, 8, 8), 256, 0, stream>>>(Qg, Kg, Vt, out);
}

// Round 4
// 136.870 us; speedup vs baseline: 1.4555x; 1.1721x over previous
//
#include <hip/hip_runtime.h>
#include <hip/hip_bf16.h>

using short4v = __attribute__((ext_vector_type(4))) short;
using short8  = __attribute__((ext_vector_type(8))) short;
using uint2v  = __attribute__((ext_vector_type(2))) unsigned int;
using f32x4   = __attribute__((ext_vector_type(4))) float;

static constexpr int CDIM = 512;
static constexpr float KSCALE = 0.125f * 1.44269504088896341f;  // scale*log2(e), folded into Q

__device__ __forceinline__ short f2bf(float f) {
  unsigned u = __builtin_bit_cast(unsigned, f);
  u = (u + 0x7fffu + ((u >> 16) & 1u)) >> 16;
  return (short)(unsigned short)u;
}
__device__ __forceinline__ unsigned pack_bf16(float a, float b) {
  return (unsigned)(unsigned short)f2bf(a) | ((unsigned)(unsigned short)f2bf(b) << 16);
}

#define GLOAD_LDS16(gp, lp)                                                              \
  __builtin_amdgcn_global_load_lds((const __attribute__((address_space(1))) void*)(gp),  \
                                   (__attribute__((address_space(3))) void*)(lp), 16, 0, 0)
#define MFMA16(a, b, c) __builtin_amdgcn_mfma_f32_16x16x32_bf16((a), (b), (c), 0, 0, 0)
#define WAIT_LGKM0() __builtin_amdgcn_s_waitcnt(0xc07f)   // lgkmcnt(0) only

// ---- fused cast+transpose for Q, KV, W in ONE launch ----
__global__ __launch_bounds__(256) void prep_transpose(const float* __restrict__ query,
                                                      const float* __restrict__ keyv,
                                                      const float* __restrict__ Wqkv,
                                                      short* __restrict__ Xq_t,
                                                      short* __restrict__ Xkv_t,
                                                      short* __restrict__ W_t) {
  __shared__ float tile[64 * 65];
  const int id = blockIdx.x;
  const float* s; short* d; int R, C, r0, c0;
  if (id < 2048) {
    const int which = id >> 10;
    int rem = id & 1023;
    const int b = rem >> 7; rem &= 127;
    R = 512; C = 1024;
    s = (which ? keyv : query) + (size_t)b * 512 * 1024;
    d = (which ? Xkv_t : Xq_t) + (size_t)b * 512 * 1024;
    r0 = (rem >> 4) * 64; c0 = (rem & 15) * 64;
  } else {
    const int rem = id - 2048;                 // 0..191
    R = 512; C = 1536; s = Wqkv; d = W_t;
    r0 = (rem / 24) * 64; c0 = (rem % 24) * 64;
  }
  const int t  = threadIdx.x;
  const int rr = t >> 4;
  const int c4 = (t & 15) * 4;
#pragma unroll
  for (int i = 0; i < 4; ++i) {
    const int r = rr + i * 16;
    f32x4 v = *(const f32x4*)(s + (size_t)(r0 + r) * C + c0 + c4);
#pragma unroll
    for (int j = 0; j < 4; ++j) tile[(c4 + j) * 65 + r] = v[j];
  }
  __syncthreads();
  const int r8 = (t & 7) * 8;
#pragma unroll
  for (int i = 0; i < 2; ++i) {
    const int c = (t >> 3) + i * 32;
    short8 pk;
#pragma unroll
    for (int j = 0; j < 8; ++j) pk[j] = f2bf(tile[c * 65 + r8 + j]);
    *(short8*)(d + (size_t)(c0 + c) * R + r0 + r8) = pk;
  }
}

// ---- QKV projection -> Qg,Kg: [bh][s][d] (Q pre-scaled by KSCALE), Vt: [bh][d][s]
__global__ __launch_bounds__(256, 3) void qkv_gemm(const short* __restrict__ Xq,
                                                   const short* __restrict__ Xkv,
                                                   const short* __restrict__ Wt,
                                                   const float* __restrict__ bias,
                                                   short* __restrict__ Qg,
                                                   short* __restrict__ Kg,
                                                   short* __restrict__ Vt) {
  __shared__ short Asm[128 * 64];               // 16 KB (BK=64)
  __shared__ short Bsm[128 * 64];
  __shared__ short epi[4 * 1152];               // per-wave 16x72 slab
  const int n0 = blockIdx.x * 128;
  const int m0 = blockIdx.y * 128;
  const short* A = (n0 < CDIM) ? Xq : Xkv;
  const int t = threadIdx.x;
  const int w = t >> 6, l = t & 63;
  const int wm = w & 1, wn = w >> 1;
  const int lc = l & 15, lr = l >> 4;

  f32x4 acc[4][4];
#pragma unroll
  for (int i = 0; i < 4; ++i)
#pragma unroll
    for (int j = 0; j < 4; ++j) acc[i][j] = (f32x4){0.f, 0.f, 0.f, 0.f};

  for (int kb = 0; kb < 8; ++kb) {
    const int k0 = kb * 64;
#pragma unroll
    for (int i = 0; i < 4; ++i) {
      const int Qi = (w * 4 + i) * 64 + l;      // slot -> row Qi>>3, k-chunk Qi&7
      const int m = Qi >> 3, kq = Qi & 7;
      GLOAD_LDS16(A  + (size_t)(m0 + m) * CDIM + k0 + kq * 8, &Asm[Qi * 8]);
      GLOAD_LDS16(Wt + (size_t)(n0 + m) * CDIM + k0 + kq * 8, &Bsm[Qi * 8]);
    }
    __syncthreads();
#pragma unroll
    for (int kc = 0; kc < 2; ++kc) {
      short8 af[4], bfr[4];
#pragma unroll
      for (int mt = 0; mt < 4; ++mt)
        af[mt] = *(const short8*)(&Asm[(wm * 64 + mt * 16 + lc) * 64 + kc * 32 + lr * 8]);
#pragma unroll
      for (int nt = 0; nt < 4; ++nt)
        bfr[nt] = *(const short8*)(&Bsm[(wn * 64 + nt * 16 + lc) * 64 + kc * 32 + lr * 8]);
#pragma unroll
      for (int mt = 0; mt < 4; ++mt)
#pragma unroll
        for (int nt = 0; nt < 4; ++nt)
          acc[mt][nt] = MFMA16(af[mt], bfr[nt], acc[mt][nt]);
    }
    __syncthreads();
  }

  // ---- epilogue ----
  const int N0 = n0 + wn * 64, M0 = m0 + wm * 64;
  const int hg = N0 >> 6;
  const int part = hg >> 3, hh = hg & 7;
  const int bb = M0 >> 10, s0 = M0 & 1023;
  float bv[4];
#pragma unroll
  for (int nt = 0; nt < 4; ++nt) bv[nt] = bias[N0 + nt * 16 + lc];
  short* slab = epi + w * 1152;

  if (part < 2) {
    const float osc = part ? 1.f : KSCALE;      // fold softmax scale into Q
    short* obase = (part ? Kg : Qg) + (size_t)(bb * 8 + hh) * 65536 + (size_t)s0 * 64;
#pragma unroll
    for (int mt = 0; mt < 4; ++mt) {
#pragma unroll
      for (int nt = 0; nt < 4; ++nt)
#pragma unroll
        for (int r = 0; r < 4; ++r)
          slab[(lr * 4 + r) * 72 + nt * 16 + lc] = f2bf((acc[mt][nt][r] + bv[nt]) * osc);
      WAIT_LGKM0();
#pragma unroll
      for (int i = 0; i < 2; ++i) {
        const int slot = i * 64 + l;
        const int m_l = slot >> 3, n8 = (slot & 7) * 8;
        short8 vv = *(const short8*)(&slab[m_l * 72 + n8]);
        *(short8*)(obase + (size_t)(mt * 16 + m_l) * 64 + n8) = vv;
      }
      WAIT_LGKM0();                             // slab reuse: reads done before next writes
    }
  } else {
    short* vbase = Vt + (size_t)(bb * 8 + hh) * 65536;
#pragma unroll
    for (int nt = 0; nt < 4; ++nt) {            // pass over 16 d-rows
#pragma unroll
      for (int mt = 0; mt < 4; ++mt)
#pragma unroll
        for (int r = 0; r < 4; ++r)
          slab[lc * 72 + mt * 16 + lr * 4 + r] = f2bf(acc[mt][nt][r] + bv[nt]);
      WAIT_LGKM0();
#pragma unroll
      for (int i = 0; i < 2; ++i) {
        const int slot = i * 64 + l;
        const int dloc = slot >> 3, ch = (slot & 7) * 8;
        short8 vv = *(const short8*)(&slab[dloc * 72 + ch]);
        *(short8*)(vbase + (size_t)(nt * 16 + dloc) * 1024 + s0 + ch) = vv;
      }
      WAIT_LGKM0();
    }
  }
}

// ---- flash attention: block = 128 q of one (b,h); no-max softmax ----
__global__ __launch_bounds__(256, 2) void flash_attn(const short* __restrict__ Qg,
                                                     const short* __restrict__ Kg,
                                                     const short* __restrict__ Vt,
                                                     float* __restrict__ out) {
  __shared__ alignas(16) short smem[17408];     // 34.8 KB: K 8K + V 8K + P 18K
  short* Ksm = smem;                            // [64 s][8 swz][8]
  short* Vsm = smem + 4096;                     // [64 d][8 swz][8]
  const int b = blockIdx.z, h = blockIdx.y;
  const int q0 = blockIdx.x * 128;
  const int bh = b * 8 + h;
  const int t = threadIdx.x;
  const int w = t >> 6, l = t & 63;
  const int quad = l >> 4, l15 = l & 15;
  short* Pw = smem + 8192 + w * 2304;           // per-wave, 2 qs slabs of [16 q][72]

  const short* Qbase = Qg + (size_t)bh * 65536;
  const short* Kbase = Kg + (size_t)bh * 65536;
  const short* Vbase = Vt + (size_t)bh * 65536;

  short8 bq[2][2];                              // Q B-frags, 2 q-subtiles
#pragma unroll
  for (int qs = 0; qs < 2; ++qs) {
    const short* qrow = Qbase + (size_t)(q0 + qs * 64 + w * 16 + l15) * 64;
    bq[qs][0] = *(const short8*)(qrow + quad * 8);
    bq[qs][1] = *(const short8*)(qrow + 32 + quad * 8);
  }

  float lp[2] = {0.f, 0.f};
  f32x4 Oac[2][4];
#pragma unroll
  for (int qs = 0; qs < 2; ++qs)
#pragma unroll
    for (int dt = 0; dt < 4; ++dt) Oac[qs][dt] = (f32x4){0.f, 0.f, 0.f, 0.f};

  for (int it = 0; it < 16; ++it) {
    const int kk0 = it * 64;
#pragma unroll
    for (int i = 0; i < 2; ++i) {
      const int Qi = (w * 2 + i) * 64 + l;
      const int sr = Qi >> 3, u = Qi & 7;       // global chunk = u^(sr&7)
      GLOAD_LDS16(Kbase + (size_t)(kk0 + sr) * 64 + (u ^ (sr & 7)) * 8, &Ksm[Qi * 8]);
      GLOAD_LDS16(Vbase + (size_t)sr * 1024 + kk0 + (u ^ (sr & 7)) * 8, &Vsm[Qi * 8]);
    }
    __syncthreads();

    // K-frags once, reused by both q-subtiles
    short8 kf[2][4];
#pragma unroll
    for (int c = 0; c < 2; ++c)
#pragma unroll
      for (int nt = 0; nt < 4; ++nt) {
        const int srow = nt * 16 + l15;
        kf[c][nt] = *(const short8*)(&Ksm[(srow * 8 + ((c * 4 + quad) ^ (srow & 7))) * 8]);
      }

    // S^T = K Q^T, then p = exp2(st) (scale pre-folded into Q), P -> LDS
#pragma unroll
    for (int qs = 0; qs < 2; ++qs) {
      f32x4 st[4];
#pragma unroll
      for (int nt = 0; nt < 4; ++nt) {
        st[nt] = (f32x4){0.f, 0.f, 0.f, 0.f};
#pragma unroll
        for (int c = 0; c < 2; ++c) st[nt] = MFMA16(kf[c][nt], bq[qs][c], st[nt]);
      }
      short* Ps = Pw + qs * 1152;
#pragma unroll
      for (int nt = 0; nt < 4; ++nt) {
        float p0 = __builtin_amdgcn_exp2f(st[nt][0]);
        float p1 = __builtin_amdgcn_exp2f(st[nt][1]);
        float p2 = __builtin_amdgcn_exp2f(st[nt][2]);
        float p3 = __builtin_amdgcn_exp2f(st[nt][3]);
        lp[qs] += (p0 + p1) + (p2 + p3);
        uint2v pk;
        pk[0] = pack_bf16(p0, p1);
        pk[1] = pack_bf16(p2, p3);
        *(uint2v*)(&Ps[l15 * 72 + (nt * 4 + quad) * 4]) = pk;
      }
    }
    WAIT_LGKM0();

    // O^T += V^T P ; V-frags shared across q-subtiles
#pragma unroll
    for (int c = 0; c < 2; ++c) {
      short8 pb0 = *(const short8*)(&Pw[l15 * 72 + (c * 8 + quad * 2) * 4]);
      short8 pb1 = *(const short8*)(&Pw[1152 + l15 * 72 + (c * 8 + quad * 2) * 4]);
#pragma unroll
      for (int dt = 0; dt < 4; ++dt) {
        const int drow = dt * 16 + l15;
        short8 vf = *(const short8*)(&Vsm[(drow * 8 + ((c * 4 + quad) ^ (drow & 7))) * 8]);
        Oac[0][dt] = MFMA16(vf, pb0, Oac[0][dt]);
        Oac[1][dt] = MFMA16(vf, pb1, Oac[1][dt]);
      }
    }
    __syncthreads();
  }

  // epilogue: reduce l over quads (deferred), normalize, store O^T
#pragma unroll
  for (int qs = 0; qs < 2; ++qs) {
    float lv = lp[qs];
    lv += __shfl_xor(lv, 16, 64);
    lv += __shfl_xor(lv, 32, 64);
    const float rinv = 1.f / lv;
    float* ob = out + ((size_t)(b * 512 + h * 64)) * 1024 + q0 + qs * 64 + w * 16 + l15;
#pragma unroll
    for (int dt = 0; dt < 4; ++dt)
#pragma unroll
      for (int r = 0; r < 4; ++r)
        ob[(size_t)(dt * 16 + quad * 4 + r) * 1024] = Oac[qs][dt][r] * rinv;
  }
}

extern "C" void kernel_launch(void* const* d_in, const int* in_sizes, int n_in,
                              void* d_out, int out_size, void* d_ws, size_t ws_size,
                              hipStream_t stream) {
  const float* query = (const float*)d_in[0];   // f32 [8,512,1024]
  const float* keyv  = (const float*)d_in[1];   // f32 [8,512,1024]
  const float* Wqkv  = (const float*)d_in[2];   // f32 [512,1536]
  const float* bqkv  = (const float*)d_in[3];   // f32 [1536]
  float* out = (float*)d_out;                   // f32 [8,512,1024]
  short* ws  = (short*)d_ws;

  short* Xq_t  = ws;               // bf16 [8192,512]
  short* Xkv_t = ws + 4194304;     // bf16 [8192,512]
  short* W_t   = ws + 8388608;     // bf16 [1536,512]
  short* Qg    = ws + 9175040;     // bf16 [64][1024][64] (pre-scaled)
  short* Kg    = ws + 13369344;    // bf16 [64][1024][64]
  short* Vt    = ws + 17563648;    // bf16 [64][64][1024]

  prep_transpose<<<dim3(2240), 256, 0, stream>>>(query, keyv, Wqkv, Xq_t, Xkv_t, W_t);
  qkv_gemm<<<dim3(12, 64, 1), 256, 0, stream>>>(Xq_t, Xkv_t, W_t, bqkv, Qg, Kg, Vt);
  flash_attn<<<dim3(8, 8, 8), 256, 0, stream>>>(Qg, Kg, Vt, out);
}

// Round 5
// 133.984 us; speedup vs baseline: 1.4869x; 1.0215x over previous
//
#include <hip/hip_runtime.h>
#include <hip/hip_bf16.h>

using short4v = __attribute__((ext_vector_type(4))) short;
using short8  = __attribute__((ext_vector_type(8))) short;
using uint2v  = __attribute__((ext_vector_type(2))) unsigned int;
using f32x4   = __attribute__((ext_vector_type(4))) float;

static constexpr int CDIM = 512;
static constexpr float KSCALE = 0.125f * 1.44269504088896341f;  // scale*log2(e), folded into Q

__device__ __forceinline__ short f2bf(float f) {
  unsigned u = __builtin_bit_cast(unsigned, f);
  u = (u + 0x7fffu + ((u >> 16) & 1u)) >> 16;
  return (short)(unsigned short)u;
}
__device__ __forceinline__ unsigned pack_bf16(float a, float b) {
  return (unsigned)(unsigned short)f2bf(a) | ((unsigned)(unsigned short)f2bf(b) << 16);
}

#define GLOAD_LDS16(gp, lp)                                                              \
  __builtin_amdgcn_global_load_lds((const __attribute__((address_space(1))) void*)(gp),  \
                                   (__attribute__((address_space(3))) void*)(lp), 16, 0, 0)
#define MFMA16(a, b, c) __builtin_amdgcn_mfma_f32_16x16x32_bf16((a), (b), (c), 0, 0, 0)
#define WAIT_LGKM0() __builtin_amdgcn_s_waitcnt(0xc07f)   // lgkmcnt(0) only

// ---- fused cast+transpose for Q, KV, W in ONE launch ----
__global__ __launch_bounds__(256) void prep_transpose(const float* __restrict__ query,
                                                      const float* __restrict__ keyv,
                                                      const float* __restrict__ Wqkv,
                                                      short* __restrict__ Xq_t,
                                                      short* __restrict__ Xkv_t,
                                                      short* __restrict__ W_t) {
  __shared__ float tile[64 * 65];
  const int id = blockIdx.x;
  const float* s; short* d; int R, C, r0, c0;
  if (id < 2048) {
    const int which = id >> 10;
    int rem = id & 1023;
    const int b = rem >> 7; rem &= 127;
    R = 512; C = 1024;
    s = (which ? keyv : query) + (size_t)b * 512 * 1024;
    d = (which ? Xkv_t : Xq_t) + (size_t)b * 512 * 1024;
    r0 = (rem >> 4) * 64; c0 = (rem & 15) * 64;
  } else {
    const int rem = id - 2048;                 // 0..191
    R = 512; C = 1536; s = Wqkv; d = W_t;
    r0 = (rem / 24) * 64; c0 = (rem % 24) * 64;
  }
  const int t  = threadIdx.x;
  const int rr = t >> 4;
  const int c4 = (t & 15) * 4;
#pragma unroll
  for (int i = 0; i < 4; ++i) {
    const int r = rr + i * 16;
    f32x4 v = *(const f32x4*)(s + (size_t)(r0 + r) * C + c0 + c4);
#pragma unroll
    for (int j = 0; j < 4; ++j) tile[(c4 + j) * 65 + r] = v[j];
  }
  __syncthreads();
  const int r8 = (t & 7) * 8;
#pragma unroll
  for (int i = 0; i < 2; ++i) {
    const int c = (t >> 3) + i * 32;
    short8 pk;
#pragma unroll
    for (int j = 0; j < 8; ++j) pk[j] = f2bf(tile[c * 65 + r8 + j]);
    *(short8*)(d + (size_t)(c0 + c) * R + r0 + r8) = pk;
  }
}

// ---- QKV projection, BM=128 BN=256 BK=64, XOR-swizzled LDS ----
//   Qg,Kg: [bh][s][d] (Q pre-scaled by KSCALE), Vt: [bh][d][s]
__global__ __launch_bounds__(256, 2) void qkv_gemm(const short* __restrict__ Xq,
                                                   const short* __restrict__ Xkv,
                                                   const short* __restrict__ Wt,
                                                   const float* __restrict__ bias,
                                                   short* __restrict__ Qg,
                                                   short* __restrict__ Kg,
                                                   short* __restrict__ Vt) {
  __shared__ short Asm[128 * 64];               // 16 KB, slot(row,u) holds chunk u^(row&7)
  __shared__ short Bsm[256 * 64];               // 32 KB
  __shared__ short epi[4 * 1152];               // per-wave 16x72 slab
  const int n0 = blockIdx.x * 256;
  const int m0 = blockIdx.y * 128;
  const short* A = (n0 < CDIM) ? Xq : Xkv;      // 512 % 256 == 0: no straddle
  const int t = threadIdx.x;
  const int w = t >> 6, l = t & 63;
  const int wm = w & 1, wn = w >> 1;
  const int lc = l & 15, lr = l >> 4;

  f32x4 acc[4][8];
#pragma unroll
  for (int i = 0; i < 4; ++i)
#pragma unroll
    for (int j = 0; j < 8; ++j) acc[i][j] = (f32x4){0.f, 0.f, 0.f, 0.f};

  for (int kb = 0; kb < 8; ++kb) {
    const int k0 = kb * 64;
#pragma unroll
    for (int i = 0; i < 4; ++i) {               // A: 1024 slots
      const int Qi = (w * 4 + i) * 64 + l;
      const int row = Qi >> 3, u = Qi & 7;
      GLOAD_LDS16(A + (size_t)(m0 + row) * CDIM + k0 + ((u ^ (row & 7)) * 8), &Asm[Qi * 8]);
    }
#pragma unroll
    for (int i = 0; i < 8; ++i) {               // B: 2048 slots
      const int Qi = (w * 8 + i) * 64 + l;
      const int row = Qi >> 3, u = Qi & 7;
      GLOAD_LDS16(Wt + (size_t)(n0 + row) * CDIM + k0 + ((u ^ (row & 7)) * 8), &Bsm[Qi * 8]);
    }
    __syncthreads();
#pragma unroll
    for (int kc = 0; kc < 2; ++kc) {
      short8 af[4], bfr[8];
#pragma unroll
      for (int mt = 0; mt < 4; ++mt) {
        const int row = wm * 64 + mt * 16 + lc;
        af[mt] = *(const short8*)(&Asm[(row * 8 + ((kc * 4 + lr) ^ (row & 7))) * 8]);
      }
#pragma unroll
      for (int nt = 0; nt < 8; ++nt) {
        const int row = wn * 128 + nt * 16 + lc;
        bfr[nt] = *(const short8*)(&Bsm[(row * 8 + ((kc * 4 + lr) ^ (row & 7))) * 8]);
      }
#pragma unroll
      for (int mt = 0; mt < 4; ++mt)
#pragma unroll
        for (int nt = 0; nt < 8; ++nt)
          acc[mt][nt] = MFMA16(af[mt], bfr[nt], acc[mt][nt]);
    }
    __syncthreads();
  }

  // ---- epilogue: wave covers 64 m x 128 n = two 64-col head-groups ----
  const int M0 = m0 + wm * 64;
  const int bb = M0 >> 10, s0 = M0 & 1023;
  const int N0 = n0 + wn * 128;
  float bv[8];
#pragma unroll
  for (int nt = 0; nt < 8; ++nt) bv[nt] = bias[N0 + nt * 16 + lc];
  short* slab = epi + w * 1152;

#pragma unroll
  for (int hi = 0; hi < 2; ++hi) {
    const int hg = (N0 >> 6) + hi;
    const int part = hg >> 3, hh = hg & 7;
    const int nb = hi * 4;
    if (part < 2) {
      const float osc = part ? 1.f : KSCALE;
      short* obase = (part ? Kg : Qg) + (size_t)(bb * 8 + hh) * 65536 + (size_t)s0 * 64;
#pragma unroll
      for (int mt = 0; mt < 4; ++mt) {
#pragma unroll
        for (int ntL = 0; ntL < 4; ++ntL)
#pragma unroll
          for (int r = 0; r < 4; ++r)
            slab[(lr * 4 + r) * 72 + ntL * 16 + lc] =
                f2bf((acc[mt][nb + ntL][r] + bv[nb + ntL]) * osc);
        WAIT_LGKM0();
#pragma unroll
        for (int i = 0; i < 2; ++i) {
          const int slot = i * 64 + l;
          const int m_l = slot >> 3, n8 = (slot & 7) * 8;
          short8 vv = *(const short8*)(&slab[m_l * 72 + n8]);
          *(short8*)(obase + (size_t)(mt * 16 + m_l) * 64 + n8) = vv;
        }
        WAIT_LGKM0();
      }
    } else {
      short* vbase = Vt + (size_t)(bb * 8 + hh) * 65536;
#pragma unroll
      for (int ntL = 0; ntL < 4; ++ntL) {
#pragma unroll
        for (int mt = 0; mt < 4; ++mt)
#pragma unroll
          for (int r = 0; r < 4; ++r)
            slab[lc * 72 + mt * 16 + lr * 4 + r] = f2bf(acc[mt][nb + ntL][r] + bv[nb + ntL]);
        WAIT_LGKM0();
#pragma unroll
        for (int i = 0; i < 2; ++i) {
          const int slot = i * 64 + l;
          const int dloc = slot >> 3, ch = (slot & 7) * 8;
          short8 vv = *(const short8*)(&slab[dloc * 72 + ch]);
          *(short8*)(vbase + (size_t)(ntL * 16 + dloc) * 1024 + s0 + ch) = vv;
        }
        WAIT_LGKM0();
      }
    }
  }
}

// ---- flash attention: block = 128 q of one (b,h); XCD-local grid ----
__global__ __launch_bounds__(256, 2) void flash_attn(const short* __restrict__ Qg,
                                                     const short* __restrict__ Kg,
                                                     const short* __restrict__ Vt,
                                                     float* __restrict__ out) {
  __shared__ alignas(16) short smem[17408];     // 34.8 KB
  short* Ksm = smem;                            // [64 s][8 swz][8]
  short* Vsm = smem + 4096;                     // [64 d][8 swz][8]
  const int bh = blockIdx.x;                    // id%8 == h: q-blocks of one bh share XCD
  const int b = bh >> 3, h = bh & 7;
  const int q0 = blockIdx.y * 128;
  const int t = threadIdx.x;
  const int w = t >> 6, l = t & 63;
  const int quad = l >> 4, l15 = l & 15;
  short* Pw = smem + 8192 + w * 2304;           // per-wave, 2 slabs [16 q][72]

  const short* Qbase = Qg + (size_t)bh * 65536;
  const short* Kbase = Kg + (size_t)bh * 65536;
  const short* Vbase = Vt + (size_t)bh * 65536;

  short8 bq[2][2];
#pragma unroll
  for (int qs = 0; qs < 2; ++qs) {
    const short* qrow = Qbase + (size_t)(q0 + qs * 64 + w * 16 + l15) * 64;
    bq[qs][0] = *(const short8*)(qrow + quad * 8);
    bq[qs][1] = *(const short8*)(qrow + 32 + quad * 8);
  }

  float lp[2] = {0.f, 0.f};
  f32x4 Oac[2][4];
#pragma unroll
  for (int qs = 0; qs < 2; ++qs)
#pragma unroll
    for (int dt = 0; dt < 4; ++dt) Oac[qs][dt] = (f32x4){0.f, 0.f, 0.f, 0.f};

  for (int it = 0; it < 16; ++it) {
    const int kk0 = it * 64;
#pragma unroll
    for (int i = 0; i < 2; ++i) {
      const int Qi = (w * 2 + i) * 64 + l;
      const int sr = Qi >> 3, u = Qi & 7;
      GLOAD_LDS16(Kbase + (size_t)(kk0 + sr) * 64 + (u ^ (sr & 7)) * 8, &Ksm[Qi * 8]);
      GLOAD_LDS16(Vbase + (size_t)sr * 1024 + kk0 + (u ^ (sr & 7)) * 8, &Vsm[Qi * 8]);
    }
    __syncthreads();

    short8 kf[2][4];
#pragma unroll
    for (int c = 0; c < 2; ++c)
#pragma unroll
      for (int nt = 0; nt < 4; ++nt) {
        const int srow = nt * 16 + l15;
        kf[c][nt] = *(const short8*)(&Ksm[(srow * 8 + ((c * 4 + quad) ^ (srow & 7))) * 8]);
      }

#pragma unroll
    for (int qs = 0; qs < 2; ++qs) {
      f32x4 st[4];
#pragma unroll
      for (int nt = 0; nt < 4; ++nt) {
        st[nt] = (f32x4){0.f, 0.f, 0.f, 0.f};
#pragma unroll
        for (int c = 0; c < 2; ++c) st[nt] = MFMA16(kf[c][nt], bq[qs][c], st[nt]);
      }
      short* Ps = Pw + qs * 1152;
#pragma unroll
      for (int nt = 0; nt < 4; ++nt) {
        float p0 = __builtin_amdgcn_exp2f(st[nt][0]);
        float p1 = __builtin_amdgcn_exp2f(st[nt][1]);
        float p2 = __builtin_amdgcn_exp2f(st[nt][2]);
        float p3 = __builtin_amdgcn_exp2f(st[nt][3]);
        lp[qs] += (p0 + p1) + (p2 + p3);
        uint2v pk;
        pk[0] = pack_bf16(p0, p1);
        pk[1] = pack_bf16(p2, p3);
        *(uint2v*)(&Ps[l15 * 72 + (nt * 4 + quad) * 4]) = pk;
      }
    }
    WAIT_LGKM0();

#pragma unroll
    for (int c = 0; c < 2; ++c) {
      short8 pb0 = *(const short8*)(&Pw[l15 * 72 + (c * 8 + quad * 2) * 4]);
      short8 pb1 = *(const short8*)(&Pw[1152 + l15 * 72 + (c * 8 + quad * 2) * 4]);
#pragma unroll
      for (int dt = 0; dt < 4; ++dt) {
        const int drow = dt * 16 + l15;
        short8 vf = *(const short8*)(&Vsm[(drow * 8 + ((c * 4 + quad) ^ (drow & 7))) * 8]);
        Oac[0][dt] = MFMA16(vf, pb0, Oac[0][dt]);
        Oac[1][dt] = MFMA16(vf, pb1, Oac[1][dt]);
      }
    }
    __syncthreads();
  }

#pragma unroll
  for (int qs = 0; qs < 2; ++qs) {
    float lv = lp[qs];
    lv += __shfl_xor(lv, 16, 64);
    lv += __shfl_xor(lv, 32, 64);
    const float rinv = 1.f / lv;
    float* ob = out + ((size_t)(b * 512 + h * 64)) * 1024 + q0 + qs * 64 + w * 16 + l15;
#pragma unroll
    for (int dt = 0; dt < 4; ++dt)
#pragma unroll
      for (int r = 0; r < 4; ++r)
        ob[(size_t)(dt * 16 + quad * 4 + r) * 1024] = Oac[qs][dt][r] * rinv;
  }
}

extern "C" void kernel_launch(void* const* d_in, const int* in_sizes, int n_in,
                              void* d_out, int out_size, void* d_ws, size_t ws_size,
                              hipStream_t stream) {
  const float* query = (const float*)d_in[0];   // f32 [8,512,1024]
  const float* keyv  = (const float*)d_in[1];   // f32 [8,512,1024]
  const float* Wqkv  = (const float*)d_in[2];   // f32 [512,1536]
  const float* bqkv  = (const float*)d_in[3];   // f32 [1536]
  float* out = (float*)d_out;                   // f32 [8,512,1024]
  short* ws  = (short*)d_ws;

  short* Xq_t  = ws;               // bf16 [8192,512]
  short* Xkv_t = ws + 4194304;     // bf16 [8192,512]
  short* W_t   = ws + 8388608;     // bf16 [1536,512]
  short* Qg    = ws + 9175040;     // bf16 [64][1024][64] (pre-scaled)
  short* Kg    = ws + 13369344;    // bf16 [64][1024][64]
  short* Vt    = ws + 17563648;    // bf16 [64][64][1024]

  prep_transpose<<<dim3(2240), 256, 0, stream>>>(query, keyv, Wqkv, Xq_t, Xkv_t, W_t);
  qkv_gemm<<<dim3(6, 64, 1), 256, 0, stream>>>(Xq_t, Xkv_t, W_t, bqkv, Qg, Kg, Vt);
  flash_attn<<<dim3(64, 8, 1), 256, 0, stream>>>(Qg, Kg, Vt, out);
}

// Round 8
// 133.165 us; speedup vs baseline: 1.4960x; 1.0061x over previous
//
#include <hip/hip_runtime.h>
#include <hip/hip_bf16.h>

using short4v = __attribute__((ext_vector_type(4))) short;
using short8  = __attribute__((ext_vector_type(8))) short;
using uint2v  = __attribute__((ext_vector_type(2))) unsigned int;
using f32x4   = __attribute__((ext_vector_type(4))) float;

static constexpr int CDIM = 512;
static constexpr float KSCALE = 0.125f * 1.44269504088896341f;  // scale*log2(e), folded into Q

// proven RNE convert (rounds 2-5)
__device__ __forceinline__ short f2bf(float f) {
  unsigned u = __builtin_bit_cast(unsigned, f);
  u = (u + 0x7fffu + ((u >> 16) & 1u)) >> 16;
  return (short)(unsigned short)u;
}
__device__ __forceinline__ unsigned pack_bf16(float a, float b) {
  return (unsigned)(unsigned short)f2bf(a) | ((unsigned)(unsigned short)f2bf(b) << 16);
}

#define GLOAD_LDS16(gp, lp)                                                              \
  __builtin_amdgcn_global_load_lds((const __attribute__((address_space(1))) void*)(gp),  \
                                   (__attribute__((address_space(3))) void*)(lp), 16, 0, 0)
#define MFMA16(a, b, c) __builtin_amdgcn_mfma_f32_16x16x32_bf16((a), (b), (c), 0, 0, 0)
#define WAIT_LGKM0() __builtin_amdgcn_s_waitcnt(0xc07f)   // lgkmcnt(0) only

// ---- fused cast+transpose for Q, KV, W in ONE launch ----
__global__ __launch_bounds__(256) void prep_transpose(const float* __restrict__ query,
                                                      const float* __restrict__ keyv,
                                                      const float* __restrict__ Wqkv,
                                                      short* __restrict__ Xq_t,
                                                      short* __restrict__ Xkv_t,
                                                      short* __restrict__ W_t) {
  __shared__ float tile[64 * 65];
  const int id = blockIdx.x;
  const float* s; short* d; int R, C, r0, c0;
  if (id < 2048) {
    const int which = id >> 10;
    int rem = id & 1023;
    const int b = rem >> 7; rem &= 127;
    R = 512; C = 1024;
    s = (which ? keyv : query) + (size_t)b * 512 * 1024;
    d = (which ? Xkv_t : Xq_t) + (size_t)b * 512 * 1024;
    r0 = (rem >> 4) * 64; c0 = (rem & 15) * 64;
  } else {
    const int rem = id - 2048;                 // 0..191
    R = 512; C = 1536; s = Wqkv; d = W_t;
    r0 = (rem / 24) * 64; c0 = (rem % 24) * 64;
  }
  const int t  = threadIdx.x;
  const int rr = t >> 4;
  const int c4 = (t & 15) * 4;
#pragma unroll
  for (int i = 0; i < 4; ++i) {
    const int r = rr + i * 16;
    f32x4 v = *(const f32x4*)(s + (size_t)(r0 + r) * C + c0 + c4);
#pragma unroll
    for (int j = 0; j < 4; ++j) tile[(c4 + j) * 65 + r] = v[j];
  }
  __syncthreads();
  const int r8 = (t & 7) * 8;
#pragma unroll
  for (int i = 0; i < 2; ++i) {
    const int c = (t >> 3) + i * 32;
    short8 pk;
#pragma unroll
    for (int j = 0; j < 8; ++j) pk[j] = f2bf(tile[c * 65 + r8 + j]);
    *(short8*)(d + (size_t)(c0 + c) * R + r0 + r8) = pk;
  }
}

// ---- QKV projection, BM=128 BN=256 BK=64, swizzled LDS, XCD-clustered grid ----
//   Qg,Kg: [bh][s][d] (Q pre-scaled by KSCALE), Vt: [bh][d][s]
__global__ __launch_bounds__(256, 2) void qkv_gemm(const short* __restrict__ Xq,
                                                   const short* __restrict__ Xkv,
                                                   const short* __restrict__ Wt,
                                                   const float* __restrict__ bias,
                                                   short* __restrict__ Qg,
                                                   short* __restrict__ Kg,
                                                   short* __restrict__ Vt) {
  __shared__ short Asm[128 * 64];               // slot(row,u) holds chunk u^(row&7)
  __shared__ short Bsm[256 * 64];
  __shared__ short epi[4 * 1152];
  // XCD clustering (bijective id permutation): id&7 = XCD; each XCD slice owns
  // 8 m-tiles x all 6 n-tiles -> A slice (1MB) + W (1.5MB) L2-resident.
  const int id = blockIdx.x;
  const int n_blk = id >> 6;
  const int m_blk = ((id & 7) << 3) | ((id >> 3) & 7);
  const int n0 = n_blk << 8;
  const int m0 = m_blk << 7;
  const short* A = (n0 < CDIM) ? Xq : Xkv;      // 512 % 256 == 0: no straddle
  const int t = threadIdx.x;
  const int w = t >> 6, l = t & 63;
  const int wm = w & 1, wn = w >> 1;
  const int lc = l & 15, lr = l >> 4;

  f32x4 acc[4][8];
#pragma unroll
  for (int i = 0; i < 4; ++i)
#pragma unroll
    for (int j = 0; j < 8; ++j) acc[i][j] = (f32x4){0.f, 0.f, 0.f, 0.f};

  for (int kb = 0; kb < 8; ++kb) {
    const int k0 = kb * 64;
#pragma unroll
    for (int i = 0; i < 4; ++i) {               // A: 1024 slots
      const int Qi = (w * 4 + i) * 64 + l;
      const int row = Qi >> 3, u = Qi & 7;
      GLOAD_LDS16(A + (size_t)(m0 + row) * CDIM + k0 + ((u ^ (row & 7)) * 8), &Asm[Qi * 8]);
    }
#pragma unroll
    for (int i = 0; i < 8; ++i) {               // B: 2048 slots
      const int Qi = (w * 8 + i) * 64 + l;
      const int row = Qi >> 3, u = Qi & 7;
      GLOAD_LDS16(Wt + (size_t)(n0 + row) * CDIM + k0 + ((u ^ (row & 7)) * 8), &Bsm[Qi * 8]);
    }
    __syncthreads();
#pragma unroll
    for (int kc = 0; kc < 2; ++kc) {
      short8 af[4], bfr[8];
#pragma unroll
      for (int mt = 0; mt < 4; ++mt) {
        const int row = wm * 64 + mt * 16 + lc;
        af[mt] = *(const short8*)(&Asm[(row * 8 + ((kc * 4 + lr) ^ (row & 7))) * 8]);
      }
#pragma unroll
      for (int nt = 0; nt < 8; ++nt) {
        const int row = wn * 128 + nt * 16 + lc;
        bfr[nt] = *(const short8*)(&Bsm[(row * 8 + ((kc * 4 + lr) ^ (row & 7))) * 8]);
      }
#pragma unroll
      for (int mt = 0; mt < 4; ++mt)
#pragma unroll
        for (int nt = 0; nt < 8; ++nt)
          acc[mt][nt] = MFMA16(af[mt], bfr[nt], acc[mt][nt]);
    }
    __syncthreads();
  }

  // ---- epilogue: wave covers 64 m x 128 n = two 64-col head-groups ----
  const int M0 = m0 + wm * 64;
  const int bb = M0 >> 10, s0 = M0 & 1023;
  const int N0 = n0 + wn * 128;
  float bv[8];
#pragma unroll
  for (int nt = 0; nt < 8; ++nt) bv[nt] = bias[N0 + nt * 16 + lc];
  short* slab = epi + w * 1152;

#pragma unroll
  for (int hi = 0; hi < 2; ++hi) {
    const int hg = (N0 >> 6) + hi;
    const int part = hg >> 3, hh = hg & 7;
    const int nb = hi * 4;
    if (part < 2) {
      const float osc = part ? 1.f : KSCALE;
      short* obase = (part ? Kg : Qg) + (size_t)(bb * 8 + hh) * 65536 + (size_t)s0 * 64;
#pragma unroll
      for (int mt = 0; mt < 4; ++mt) {
#pragma unroll
        for (int ntL = 0; ntL < 4; ++ntL)
#pragma unroll
          for (int r = 0; r < 4; ++r)
            slab[(lr * 4 + r) * 72 + ntL * 16 + lc] =
                f2bf((acc[mt][nb + ntL][r] + bv[nb + ntL]) * osc);
        WAIT_LGKM0();
#pragma unroll
        for (int i = 0; i < 2; ++i) {
          const int slot = i * 64 + l;
          const int m_l = slot >> 3, n8 = (slot & 7) * 8;
          short8 vv = *(const short8*)(&slab[m_l * 72 + n8]);
          *(short8*)(obase + (size_t)(mt * 16 + m_l) * 64 + n8) = vv;
        }
        WAIT_LGKM0();
      }
    } else {
      short* vbase = Vt + (size_t)(bb * 8 + hh) * 65536;
#pragma unroll
      for (int ntL = 0; ntL < 4; ++ntL) {
#pragma unroll
        for (int mt = 0; mt < 4; ++mt)
#pragma unroll
          for (int r = 0; r < 4; ++r)
            slab[lc * 72 + mt * 16 + lr * 4 + r] = f2bf(acc[mt][nb + ntL][r] + bv[nb + ntL]);
        WAIT_LGKM0();
#pragma unroll
        for (int i = 0; i < 2; ++i) {
          const int slot = i * 64 + l;
          const int dloc = slot >> 3, ch = (slot & 7) * 8;
          short8 vv = *(const short8*)(&slab[dloc * 72 + ch]);
          *(short8*)(vbase + (size_t)(ntL * 16 + dloc) * 1024 + s0 + ch) = vv;
        }
        WAIT_LGKM0();
      }
    }
  }
}

// ---- flash attention: 128 q per block; 2 k-tiles staged per VMEM burst,
//      __syncthreads() between halves (full compiler fence: every LDS
//      write->read crossing is barrier-protected — the r6/r7 regression was
//      the unfenced half transition) ----
__global__ __launch_bounds__(256, 2) void flash_attn(const short* __restrict__ Qg,
                                                     const short* __restrict__ Kg,
                                                     const short* __restrict__ Vt,
                                                     float* __restrict__ out) {
  __shared__ alignas(16) short smem[25600];     // 51.2 KB: K 16K + V 16K + P 18.4K
  short* Ksm = smem;                            // 2 x [64 s][8 swz][8]
  short* Vsm = smem + 8192;                     // 2 x [64 d][8 swz][8]
  const int bh = blockIdx.x;                    // id%8 == h: q-blocks of one bh share XCD
  const int b = bh >> 3, h = bh & 7;
  const int q0 = blockIdx.y * 128;
  const int t = threadIdx.x;
  const int w = t >> 6, l = t & 63;
  const int quad = l >> 4, l15 = l & 15;
  short* Pw = smem + 16384 + w * 2304;          // per-wave, 2 slabs [16 q][72]

  const short* Qbase = Qg + (size_t)bh * 65536;
  const short* Kbase = Kg + (size_t)bh * 65536;
  const short* Vbase = Vt + (size_t)bh * 65536;

  short8 bq[2][2];
#pragma unroll
  for (int qs = 0; qs < 2; ++qs) {
    const short* qrow = Qbase + (size_t)(q0 + qs * 64 + w * 16 + l15) * 64;
    bq[qs][0] = *(const short8*)(qrow + quad * 8);
    bq[qs][1] = *(const short8*)(qrow + 32 + quad * 8);
  }

  float lp[2] = {0.f, 0.f};
  f32x4 Oac[2][4];
#pragma unroll
  for (int qs = 0; qs < 2; ++qs)
#pragma unroll
    for (int dt = 0; dt < 4; ++dt) Oac[qs][dt] = (f32x4){0.f, 0.f, 0.f, 0.f};

  for (int it2 = 0; it2 < 8; ++it2) {
#pragma unroll
    for (int half = 0; half < 2; ++half) {
      const int kk0 = (it2 * 2 + half) * 64;
      short* Kd = Ksm + half * 4096;
      short* Vd = Vsm + half * 4096;
#pragma unroll
      for (int i = 0; i < 2; ++i) {
        const int Qi = (w * 2 + i) * 64 + l;
        const int sr = Qi >> 3, u = Qi & 7;
        GLOAD_LDS16(Kbase + (size_t)(kk0 + sr) * 64 + (u ^ (sr & 7)) * 8, &Kd[Qi * 8]);
        GLOAD_LDS16(Vbase + (size_t)sr * 1024 + kk0 + (u ^ (sr & 7)) * 8, &Vd[Qi * 8]);
      }
    }
    __syncthreads();

#pragma unroll
    for (int half = 0; half < 2; ++half) {
      const short* Kh = Ksm + half * 4096;
      const short* Vh = Vsm + half * 4096;
      short8 kf[2][4];
#pragma unroll
      for (int c = 0; c < 2; ++c)
#pragma unroll
        for (int nt = 0; nt < 4; ++nt) {
          const int srow = nt * 16 + l15;
          kf[c][nt] = *(const short8*)(&Kh[(srow * 8 + ((c * 4 + quad) ^ (srow & 7))) * 8]);
        }

#pragma unroll
      for (int qs = 0; qs < 2; ++qs) {
        f32x4 st[4];
#pragma unroll
        for (int nt = 0; nt < 4; ++nt) {
          st[nt] = (f32x4){0.f, 0.f, 0.f, 0.f};
#pragma unroll
          for (int c = 0; c < 2; ++c) st[nt] = MFMA16(kf[c][nt], bq[qs][c], st[nt]);
        }
        short* Ps = Pw + qs * 1152;
#pragma unroll
        for (int nt = 0; nt < 4; ++nt) {
          float p0 = __builtin_amdgcn_exp2f(st[nt][0]);
          float p1 = __builtin_amdgcn_exp2f(st[nt][1]);
          float p2 = __builtin_amdgcn_exp2f(st[nt][2]);
          float p3 = __builtin_amdgcn_exp2f(st[nt][3]);
          lp[qs] += (p0 + p1) + (p2 + p3);
          uint2v pk;
          pk[0] = pack_bf16(p0, p1);
          pk[1] = pack_bf16(p2, p3);
          // short-typed store: alias-compatible with the short8 reads below
          *(short4v*)(&Ps[l15 * 72 + (nt * 4 + quad) * 4]) = __builtin_bit_cast(short4v, pk);
        }
      }
      WAIT_LGKM0();

#pragma unroll
      for (int c = 0; c < 2; ++c) {
        short8 pb0 = *(const short8*)(&Pw[l15 * 72 + (c * 8 + quad * 2) * 4]);
        short8 pb1 = *(const short8*)(&Pw[1152 + l15 * 72 + (c * 8 + quad * 2) * 4]);
#pragma unroll
        for (int dt = 0; dt < 4; ++dt) {
          const int drow = dt * 16 + l15;
          short8 vf = *(const short8*)(&Vh[(drow * 8 + ((c * 4 + quad) ^ (drow & 7))) * 8]);
          Oac[0][dt] = MFMA16(vf, pb0, Oac[0][dt]);
          Oac[1][dt] = MFMA16(vf, pb1, Oac[1][dt]);
        }
      }
      __syncthreads();                          // full fence: protects P and K/V reuse
    }
  }

#pragma unroll
  for (int qs = 0; qs < 2; ++qs) {
    float lv = lp[qs];
    lv += __shfl_xor(lv, 16, 64);
    lv += __shfl_xor(lv, 32, 64);
    const float rinv = 1.f / lv;
    float* ob = out + ((size_t)(b * 512 + h * 64)) * 1024 + q0 + qs * 64 + w * 16 + l15;
#pragma unroll
    for (int dt = 0; dt < 4; ++dt)
#pragma unroll
      for (int r = 0; r < 4; ++r)
        ob[(size_t)(dt * 16 + quad * 4 + r) * 1024] = Oac[qs][dt][r] * rinv;
  }
}

extern "C" void kernel_launch(void* const* d_in, const int* in_sizes, int n_in,
                              void* d_out, int out_size, void* d_ws, size_t ws_size,
                              hipStream_t stream) {
  const float* query = (const float*)d_in[0];   // f32 [8,512,1024]
  const float* keyv  = (const float*)d_in[1];   // f32 [8,512,1024]
  const float* Wqkv  = (const float*)d_in[2];   // f32 [512,1536]
  const float* bqkv  = (const float*)d_in[3];   // f32 [1536]
  float* out = (float*)d_out;                   // f32 [8,512,1024]
  short* ws  = (short*)d_ws;

  short* Xq_t  = ws;               // bf16 [8192,512]
  short* Xkv_t = ws + 4194304;     // bf16 [8192,512]
  short* W_t   = ws + 8388608;     // bf16 [1536,512]
  short* Qg    = ws + 9175040;     // bf16 [64][1024][64] (pre-scaled)
  short* Kg    = ws + 13369344;    // bf16 [64][1024][64]
  short* Vt    = ws + 17563648;    // bf16 [64][64][1024]

  prep_transpose<<<dim3(2240), 256, 0, stream>>>(query, keyv, Wqkv, Xq_t, Xkv_t, W_t);
  qkv_gemm<<<dim3(384), 256, 0, stream>>>(Xq_t, Xkv_t, W_t, bqkv, Qg, Kg, Vt);
  flash_attn<<<dim3(64, 8, 1), 256, 0, stream>>>(Qg, Kg, Vt, out);
}